// Round 20
// baseline (82.431 us; speedup 1.0000x reference)
//
#include <hip/hip_runtime.h>
#include <hip/hip_bf16.h>
#include <math.h>

// Problem constants
#define NPIX 9216   // 96*96
#define HDIM 96
#define WDIM 96
#define NHEADS 6
#define BATCH 4

typedef _Float16 f16x8 __attribute__((ext_vector_type(8)));
typedef float    f32x4 __attribute__((ext_vector_type(4)));

struct Bias6 { const float* p[6]; };

// async global->LDS 16B copy (dest: wave-uniform base + lane*16)
__device__ __forceinline__ void cp16(void* ldst, const void* gsrc) {
    __builtin_amdgcn_global_load_lds(
        (const __attribute__((address_space(1))) unsigned int*)gsrc,
        (__attribute__((address_space(3))) unsigned int*)ldst, 16, 0, 0);
}

__device__ __forceinline__ unsigned packf16(float a, float b) {
    _Float16 ha = (_Float16)a, hb = (_Float16)b;
    return (unsigned)*(unsigned short*)&ha | ((unsigned)*(unsigned short*)&hb << 16);
}

template<int N>
__device__ __forceinline__ void waitcnt_vm() {
    if constexpr (N == 0) asm volatile("s_waitcnt vmcnt(0)" ::: "memory");
    else if constexpr (N == 2) asm volatile("s_waitcnt vmcnt(2)" ::: "memory");
    else if constexpr (N == 3) asm volatile("s_waitcnt vmcnt(3)" ::: "memory");
    else if constexpr (N == 4) asm volatile("s_waitcnt vmcnt(4)" ::: "memory");
    else if constexpr (N == 5) asm volatile("s_waitcnt vmcnt(5)" ::: "memory");
    else asm volatile("s_waitcnt vmcnt(0)" ::: "memory");
    __builtin_amdgcn_sched_barrier(0);
}

// v_fma_mix_f32: acc += f16half(src0) * {f16half|f32}(src1), f32 accumulate.
#define MIX_LL(acc, kk, qq) asm("v_fma_mix_f32 %0, %1, %2, %0 op_sel:[0,0,0] op_sel_hi:[1,1,0]" : "+v"(acc) : "v"(kk), "v"(qq))
#define MIX_HH(acc, kk, qq) asm("v_fma_mix_f32 %0, %1, %2, %0 op_sel:[1,1,0] op_sel_hi:[1,1,0]" : "+v"(acc) : "v"(kk), "v"(qq))
#define MIX_LF(acc, vv, ee) asm("v_fma_mix_f32 %0, %1, %2, %0 op_sel:[0,0,0] op_sel_hi:[1,0,0]" : "+v"(acc) : "v"(vv), "v"(ee))
#define MIX_HF(acc, vv, ee) asm("v_fma_mix_f32 %0, %1, %2, %0 op_sel:[1,0,0] op_sel_hi:[1,0,0]" : "+v"(acc) : "v"(vv), "v"(ee))

// ---------------------------------------------------------------------------
// x transpose+convert: [B][192][NPIX] fp32 -> records [B][NPIX][192] f16.
// The y==0,z==0 block slice also converts both weight matrices to f16, and
// block (0,0,0) zeroes the OOB guard page.
// ---------------------------------------------------------------------------
__global__ __launch_bounds__(256) void convert_x(
    const float* __restrict__ x, _Float16* __restrict__ Xf,
    const float* __restrict__ w1, _Float16* __restrict__ Wf1,
    const float* __restrict__ w2, _Float16* __restrict__ Wf2,
    uint4* __restrict__ guard)
{
    __shared__ float t[32][65];
    const int b  = blockIdx.z;
    const int c0 = blockIdx.y * 32;
    const int p0 = blockIdx.x * 64;
    const int tid = threadIdx.x;

    if (blockIdx.y == 0 && blockIdx.z == 0) {
        const int f = blockIdx.x * 256 + tid;    // 0..36863
        #pragma unroll
        for (int u = 0; u < 4; ++u) {
            const int i = f * 4 + u;             // 0..147455
            if (i < 576 * 192) Wf1[i] = (_Float16)w1[i];
            else               Wf2[i - 576 * 192] = (_Float16)w2[i - 576 * 192];
        }
        if (blockIdx.x == 0 && tid < 64)
            guard[tid] = make_uint4(0u, 0u, 0u, 0u);
    }

    const int pl = tid & 63;
    #pragma unroll
    for (int i = 0; i < 8; ++i) {
        const int c = i * 4 + (tid >> 6);
        t[c][pl] = x[((size_t)b * 192 + c0 + c) * NPIX + p0 + pl];
    }
    __syncthreads();
    const int p  = tid >> 2;
    const int cq = (tid & 3) * 8;
    f16x8 vh;
    #pragma unroll
    for (int j = 0; j < 8; ++j)
        vh[j] = (_Float16)t[cq + j][p];
    *(f16x8*)(Xf + ((size_t)b * NPIX + p0 + p) * 192 + c0 + cq) = vh;
}

// ---------------------------------------------------------------------------
// f16 MFMA GEMM (1-product): Y[b][m][n] = sum_k W[m][k] * X[b][n][k]
// m97 structure: BM=64 BN=128 BK=64; global_load_lds staging + chunk-XOR swizzle.
// 1D grid, XCD-owned n-ranges: XCD x owns n-tiles [9x, 9x+9).
// MODE 0: Y float planes [B][M][NPIX].  MODE 1: f16 octet-planes [B][M/8][NPIX] x uint4.
// ---------------------------------------------------------------------------
template<int MODE, int M>
__global__ __launch_bounds__(256) void gemm_mfma(
    const _Float16* __restrict__ A, const _Float16* __restrict__ B,
    void* __restrict__ Yv)
{
    constexpr int MT = M / 64;                  // m-tiles
    __shared__ _Float16 sA[64 * 64];            // 8 KB
    __shared__ _Float16 sB[128 * 64];           // 16 KB

    const int orig = blockIdx.x;
    const int xcd = orig & 7;
    const int l = orig >> 3;                    // 0 .. MT*4*9-1
    const int m0 = (l % MT) * 64;
    const int b  = (l / MT) & 3;
    const int n0 = (xcd * 9 + l / (MT * 4)) * 128;

    const int tid  = threadIdx.x;
    const int lane = tid & 63;
    const int wid  = tid >> 6;
    const int wr = wid >> 1, wc = wid & 1;
    const int lr = lane & 15;
    const int kg = lane >> 4;

    const char* gA = (const char*)A + (size_t)m0 * 384;
    const char* gB = (const char*)B + ((size_t)b * NPIX + n0) * 384;

    f32x4 acc[2][4];
    #pragma unroll
    for (int mf = 0; mf < 2; ++mf)
        #pragma unroll
        for (int nf = 0; nf < 4; ++nf)
            acc[mf][nf] = (f32x4){0.f, 0.f, 0.f, 0.f};

    for (int ks = 0; ks < 3; ++ks) {
        if (ks) __syncthreads();
        const int kb = ks * 128;
        #pragma unroll
        for (int it = 0; it < 2; ++it) {
            const int d  = it * 256 + tid;
            const int rd = d >> 3, cd = d & 7;
            const size_t src = (size_t)rd * 384 + kb + ((cd ^ (rd & 7)) << 4);
            cp16((char*)sA + d * 16, gA + src);
        }
        #pragma unroll
        for (int it = 0; it < 4; ++it) {
            const int d  = it * 256 + tid;
            const int rd = d >> 3, cd = d & 7;
            const size_t src = (size_t)rd * 384 + kb + ((cd ^ (rd & 7)) << 4);
            cp16((char*)sB + d * 16, gB + src);
        }
        __syncthreads();
        #pragma unroll
        for (int s = 0; s < 2; ++s) {
            f16x8 aH[2], bH[4];
            #pragma unroll
            for (int mf = 0; mf < 2; ++mf) {
                const int row = wr * 32 + mf * 16 + lr;
                const int c = (s * 4 + kg) ^ (row & 7);
                aH[mf] = *(const f16x8*)((const char*)sA + row * 128 + c * 16);
            }
            #pragma unroll
            for (int nf = 0; nf < 4; ++nf) {
                const int row = wc * 64 + nf * 16 + lr;
                const int c = (s * 4 + kg) ^ (row & 7);
                bH[nf] = *(const f16x8*)((const char*)sB + row * 128 + c * 16);
            }
            #pragma unroll
            for (int mf = 0; mf < 2; ++mf)
                #pragma unroll
                for (int nf = 0; nf < 4; ++nf)
                    acc[mf][nf] = __builtin_amdgcn_mfma_f32_16x16x32_f16(aH[mf], bH[nf], acc[mf][nf], 0, 0, 0);
        }
    }

    // D layout: col = lane&15, row = (lane>>4)*4 + r
    if (MODE == 0) {
        float* Yb = (float*)Yv + ((size_t)b * M + m0 + wr * 32) * NPIX + n0 + wc * 64;
        #pragma unroll
        for (int mf = 0; mf < 2; ++mf)
            #pragma unroll
            for (int r = 0; r < 4; ++r) {
                const int row = mf * 16 + kg * 4 + r;
                #pragma unroll
                for (int nf = 0; nf < 4; ++nf)
                    Yb[(size_t)row * NPIX + nf * 16 + lr] = acc[mf][nf][r];
            }
    } else {
        #pragma unroll
        for (int mf = 0; mf < 2; ++mf) {
            const int cbase = m0 + wr * 32 + mf * 16 + kg * 4;
            unsigned* Yq = (unsigned*)Yv
                + (((size_t)b * 72 + (cbase >> 3)) * NPIX + n0 + wc * 64 + lr) * 4
                + ((kg & 1) << 1);
            #pragma unroll
            for (int nf = 0; nf < 4; ++nf) {
                Yq[(nf * 16) * 4 + 0] = packf16(acc[mf][nf][0], acc[mf][nf][1]);
                Yq[(nf * 16) * 4 + 1] = packf16(acc[mf][nf][2], acc[mf][nf][3]);
            }
        }
    }
}

// ---------------------------------------------------------------------------
// LDS-tiled neighborhood attention, f16 octet planes. 32x8 tiles, 256 thr,
// 864 blocks XCD-chunked. Round-12 geometry (bufs 2560 entries: heads
// 0,1,2,4 AND (9,2) on the counted-vmcnt double-buffered path; only (7,3)
// single-buffer syncthreads) + setprio bursts + per-head BORDER fast staging.
// 8 rounds: r=0..3 QK octets, r=4..7 PV octets. Output f16 records.
// ---------------------------------------------------------------------------
#define TW 32
#define TH 8

template<int KSZ, int DIL, bool DB, int L, bool BORDER>
__device__ __forceinline__ void attn_body(
    const uint4* __restrict__ Qq, const uint4* __restrict__ Kq,
    const uint4* __restrict__ Vq, const float* __restrict__ bias,
    const uint4* __restrict__ guard,
    _Float16* __restrict__ oh, int h0, int w0,
    uint4* __restrict__ bufs,
    unsigned (* __restrict__ out_lds)[256])
{
    constexpr int CC  = KSZ / 2;
    constexpr int HAL = CC * DIL;
    constexpr int R   = TH + 2 * HAL;
    constexpr int C   = TW + 2 * HAL;
    constexpr int RC  = R * C;
    constexpr int NN  = KSZ * KSZ;

    const int tid = threadIdx.x;
    const int tx = tid & 31;
    const int ty = tid >> 5;               // 0..7
    const int pix = (h0 + ty) * WDIM + (w0 + tx);
    const int lb = ty * C + tx;

    uint4 qv[4];
    #pragma unroll
    for (int p = 0; p < 4; ++p) qv[p] = Qq[(size_t)p * NPIX + pix];

    // bias folded into score init: e = exp2((dot + bias/scale) * scale*log2e)
    float score[NN];
    #pragma unroll
    for (int n = 0; n < NN; ++n) score[n] = bias[n] * 5.656854249492381f;

    auto STAGE = [&](int r) {
        const uint4* src = (r < 4) ? (Kq + (size_t)r * NPIX)
                                   : (Vq + (size_t)(r - 4) * NPIX);
        uint4* dst = bufs + (DB ? ((r & 1) * (L * 256)) : 0);
        #pragma unroll
        for (int it = 0; it < L; ++it) {
            const int idx = it * 256 + tid;
            const int rr = idx / C, cc = idx - rr * C;
            const int gh = h0 - HAL + rr, gw = w0 - HAL + cc;
            if constexpr (BORDER) {
                const bool ok = (idx < RC) && ((unsigned)gh < (unsigned)HDIM)
                                           && ((unsigned)gw < (unsigned)WDIM);
                const uint4* s = ok ? (src + gh * WDIM + gw) : guard;
                cp16(dst + idx, s);
            } else {
                if (idx < RC) cp16(dst + idx, src + gh * WDIM + gw);
            }
        }
    };

    auto QK = [&](const uint4* buf, int oct) {
        const uint4 q = qv[oct];
        __builtin_amdgcn_s_setprio(1);
        #pragma unroll
        for (int i = 0; i < KSZ; ++i)
            #pragma unroll
            for (int j = 0; j < KSZ; ++j) {
                const uint4 k8 = buf[lb + i * DIL * C + j * DIL];
                float s = score[i * KSZ + j];
                MIX_LL(s, k8.x, q.x); MIX_HH(s, k8.x, q.x);
                MIX_LL(s, k8.y, q.y); MIX_HH(s, k8.y, q.y);
                MIX_LL(s, k8.z, q.z); MIX_HH(s, k8.z, q.z);
                MIX_LL(s, k8.w, q.w); MIX_HH(s, k8.w, q.w);
                score[i * KSZ + j] = s;
            }
        __builtin_amdgcn_s_setprio(0);
    };

    float inv = 0.f;
    auto SOFTMAX = [&]() {
        float l = 0.f;
        #pragma unroll
        for (int n = 0; n < NN; ++n) {
            // scale * log2(e)
            const float e = exp2f(score[n] * 0.25506113952980654f);
            l += e;
            score[n] = e;
        }
        inv = 1.f / l;
    };

    auto PV = [&](const uint4* buf, int oct) {
        float a0 = 0.f, a1 = 0.f, a2 = 0.f, a3 = 0.f;
        float a4 = 0.f, a5 = 0.f, a6 = 0.f, a7 = 0.f;
        __builtin_amdgcn_s_setprio(1);
        #pragma unroll
        for (int i = 0; i < KSZ; ++i)
            #pragma unroll
            for (int j = 0; j < KSZ; ++j) {
                const uint4 v8 = buf[lb + i * DIL * C + j * DIL];
                const float e = score[i * KSZ + j];
                MIX_LF(a0, v8.x, e); MIX_HF(a1, v8.x, e);
                MIX_LF(a2, v8.y, e); MIX_HF(a3, v8.y, e);
                MIX_LF(a4, v8.z, e); MIX_HF(a5, v8.z, e);
                MIX_LF(a6, v8.w, e); MIX_HF(a7, v8.w, e);
            }
        __builtin_amdgcn_s_setprio(0);
        const int rr = oct & 1;
        out_lds[rr * 4 + 0][tid] = packf16(a0 * inv, a1 * inv);
        out_lds[rr * 4 + 1][tid] = packf16(a2 * inv, a3 * inv);
        out_lds[rr * 4 + 2][tid] = packf16(a4 * inv, a5 * inv);
        out_lds[rr * 4 + 3][tid] = packf16(a6 * inv, a7 * inv);
    };

    auto COOP = [&](int half) {     // coalesced half-record write (16 ch)
        #pragma unroll
        for (int it = 0; it < 2; ++it) {
            const int linear = it * 256 + tid;
            const int px = linear >> 1;        // 0..255
            const int c  = linear & 1;
            const int gpix = (h0 + (px >> 5)) * WDIM + w0 + (px & 31);
            uint4 val = make_uint4(out_lds[c * 4 + 0][px], out_lds[c * 4 + 1][px],
                                   out_lds[c * 4 + 2][px], out_lds[c * 4 + 3][px]);
            *((uint4*)((unsigned*)(oh + (size_t)gpix * 192)) + half * 2 + c) = val;
        }
    };

    if constexpr (DB) {
        STAGE(0);
        #pragma unroll
        for (int r = 0; r < 8; ++r) {
            if (r < 7) STAGE(r + 1);
            if (r < 7) waitcnt_vm<L>(); else waitcnt_vm<0>();
            __builtin_amdgcn_s_barrier();
            __builtin_amdgcn_sched_barrier(0);
            const uint4* buf = bufs + (r & 1) * (L * 256);
            if (r < 4) {
                QK(buf, r);
                if (r == 3) SOFTMAX();
            } else {
                PV(buf, r - 4);
                asm volatile("s_waitcnt lgkmcnt(0)" ::: "memory");
                __builtin_amdgcn_sched_barrier(0);
            }
            __builtin_amdgcn_s_barrier();
            __builtin_amdgcn_sched_barrier(0);
            if (r == 5) COOP(0);
            if (r == 7) COOP(1);
        }
    } else {
        #pragma unroll
        for (int r = 0; r < 8; ++r) {
            __syncthreads();
            if (r == 6) COOP(0);
            STAGE(r);
            __syncthreads();
            const uint4* buf = bufs;
            if (r < 4) {
                QK(buf, r);
                if (r == 3) SOFTMAX();
            } else {
                PV(buf, r - 4);
            }
        }
        __syncthreads();
        COOP(1);
    }
}

// 864 blocks, XCD-chunked: XCD x owns wgs [x*108,(x+1)*108) = 3 panels
// (big/mid/small k) x 36 tiles of 32x8. Tiles whose full halo is in-bounds
// for their head's HAL take the unguarded staging path.
__global__ __launch_bounds__(256) void attn_kernel(
    const uint4* __restrict__ qkv, Bias6 bs, _Float16* __restrict__ ATf,
    const uint4* __restrict__ guard)
{
    __shared__ uint4 bufs[2560];             // 40 KB (DB L<=5; sync (7,3) 1300)
    __shared__ unsigned out_lds[8][256];     // 8 KB  -> 48 KB total, 3 blk/CU

    const int orig = blockIdx.x;
    const int wg = (orig & 7) * 108 + (orig >> 3);
    const int panel = wg / 36;
    const int tile = wg - panel * 36;
    const int chunk = panel / 3, slot = panel - chunk * 3;
    int head, b;
    if (slot == 0)      { head = 4 + (chunk >> 2); b = chunk & 3; }
    else if (slot == 1) { head = 2 + (chunk >> 2); b = chunk & 3; }
    else                { head = (chunk < 4) ? 1 : 0; b = chunk & 3; }
    const int txt = tile % 3, tyt = tile / 3;   // 3 x 12 tiles of 32x8
    const int w0 = txt * TW, h0 = tyt * TH;

    const int halA[6] = {1, 4, 3, 9, 4, 8};
    const int hal = halA[head];
    const bool border = (w0 < hal) | (w0 + TW + hal > WDIM)
                      | (h0 < hal) | (h0 + TH + hal > HDIM);

    const uint4* base = qkv + (size_t)b * 72 * NPIX;
    const uint4* Qq = base + (size_t)(head * 4) * NPIX;
    const uint4* Kq = base + (size_t)(24 + head * 4) * NPIX;
    const uint4* Vq = base + (size_t)(48 + head * 4) * NPIX;
    _Float16* oh = ATf + (size_t)b * NPIX * 192 + head * 32;
    const float* bias = bs.p[head];

    if (border) {
        switch (head) {
            case 0: attn_body<3, 1, true, 2, true>(Qq, Kq, Vq, bias, guard, oh, h0, w0, bufs, out_lds); break;
            case 1: attn_body<5, 2, true, 3, true>(Qq, Kq, Vq, bias, guard, oh, h0, w0, bufs, out_lds); break;
            case 2: attn_body<7, 1, true, 3, true>(Qq, Kq, Vq, bias, guard, oh, h0, w0, bufs, out_lds); break;
            case 3: attn_body<7, 3, false, 6, true>(Qq, Kq, Vq, bias, guard, oh, h0, w0, bufs, out_lds); break;
            case 4: attn_body<9, 1, true, 3, true>(Qq, Kq, Vq, bias, guard, oh, h0, w0, bufs, out_lds); break;
            case 5: attn_body<9, 2, true, 5, true>(Qq, Kq, Vq, bias, guard, oh, h0, w0, bufs, out_lds); break;
        }
    } else {
        switch (head) {
            case 0: attn_body<3, 1, true, 2, false>(Qq, Kq, Vq, bias, guard, oh, h0, w0, bufs, out_lds); break;
            case 1: attn_body<5, 2, true, 3, false>(Qq, Kq, Vq, bias, guard, oh, h0, w0, bufs, out_lds); break;
            case 2: attn_body<7, 1, true, 3, false>(Qq, Kq, Vq, bias, guard, oh, h0, w0, bufs, out_lds); break;
            case 3: attn_body<7, 3, false, 6, false>(Qq, Kq, Vq, bias, guard, oh, h0, w0, bufs, out_lds); break;
            case 4: attn_body<9, 1, true, 3, false>(Qq, Kq, Vq, bias, guard, oh, h0, w0, bufs, out_lds); break;
            case 5: attn_body<9, 2, true, 5, false>(Qq, Kq, Vq, bias, guard, oh, h0, w0, bufs, out_lds); break;
        }
    }
}

// ---------------------------------------------------------------------------
extern "C" void kernel_launch(void* const* d_in, const int* in_sizes, int n_in,
                              void* d_out, int out_size, void* d_ws, size_t ws_size,
                              hipStream_t stream) {
    const float* x     = (const float*)d_in[0];   // [4][192][96][96]
    const float* w_qkv = (const float*)d_in[1];   // [576][192]
    const float* w_out = (const float*)d_in[2];   // [192][192]
    Bias6 bs;
    for (int i = 0; i < 6; ++i) bs.p[i] = (const float*)d_in[3 + i];
    float* out = (float*)d_out;                   // [4][192][96][96]

    char* ws = (char*)d_ws;
    uint4*    QKV = (uint4*)ws;         ws += (size_t)BATCH * 72 * NPIX * 16;   // 42.5 MB
    _Float16* Xf  = (_Float16*)ws;      ws += (size_t)BATCH * NPIX * 192 * 2;   // 14.2 MB
    _Float16* ATf = (_Float16*)ws;      ws += (size_t)BATCH * NPIX * 192 * 2;   // 14.2 MB
    _Float16* Wf1 = (_Float16*)ws;      ws += (size_t)576 * 192 * 2;
    _Float16* Wf2 = (_Float16*)ws;      ws += (size_t)192 * 192 * 2;
    uint4* guard  = (uint4*)ws;         ws += 1024;                              // zero page

    // 1) x transpose+convert to f16 records (+ weight convert + guard zero)
    convert_x<<<dim3(NPIX / 64, 192 / 32, BATCH), 256, 0, stream>>>(
        x, Xf, w_qkv, Wf1, w_out, Wf2, guard);

    // 2) qkv projection (f16 MFMA) -> f16 octet-planes [B][72][NPIX] x uint4
    gemm_mfma<1, 576><<<dim3(8 * (576 / 64) * 4 * 9), 256, 0, stream>>>(
        Wf1, Xf, (void*)QKV);

    // 3) neighborhood attention -> f16 records (coalesced)
    attn_kernel<<<dim3(864), 256, 0, stream>>>(QKV, bs, ATf, guard);

    // 4) out projection (f16 MFMA) -> d_out fp32 planes
    gemm_mfma<0, 192><<<dim3(8 * (192 / 64) * 4 * 9), 256, 0, stream>>>(
        Wf2, ATf, (void*)out);
}

// Round 23
// 81.661 us; speedup vs baseline: 1.0094x; 1.0094x over previous
//
#include <hip/hip_runtime.h>
#include <hip/hip_bf16.h>
#include <math.h>

// Problem constants
#define NPIX 9216   // 96*96
#define HDIM 96
#define WDIM 96
#define NHEADS 6
#define BATCH 4

typedef _Float16 f16x8 __attribute__((ext_vector_type(8)));
typedef float    f32x4 __attribute__((ext_vector_type(4)));

struct Bias6 { const float* p[6]; };

// async global->LDS 16B copy (dest: wave-uniform base + lane*16)
__device__ __forceinline__ void cp16(void* ldst, const void* gsrc) {
    __builtin_amdgcn_global_load_lds(
        (const __attribute__((address_space(1))) unsigned int*)gsrc,
        (__attribute__((address_space(3))) unsigned int*)ldst, 16, 0, 0);
}

__device__ __forceinline__ unsigned packf16(float a, float b) {
    _Float16 ha = (_Float16)a, hb = (_Float16)b;
    return (unsigned)*(unsigned short*)&ha | ((unsigned)*(unsigned short*)&hb << 16);
}

template<int N>
__device__ __forceinline__ void waitcnt_vm() {
    if constexpr (N == 0) asm volatile("s_waitcnt vmcnt(0)" ::: "memory");
    else if constexpr (N == 2) asm volatile("s_waitcnt vmcnt(2)" ::: "memory");
    else if constexpr (N == 3) asm volatile("s_waitcnt vmcnt(3)" ::: "memory");
    else if constexpr (N == 4) asm volatile("s_waitcnt vmcnt(4)" ::: "memory");
    else asm volatile("s_waitcnt vmcnt(0)" ::: "memory");
    __builtin_amdgcn_sched_barrier(0);
}

// v_fma_mix_f32: acc += f16half(src0) * {f16half|f32}(src1), f32 accumulate.
#define MIX_LL(acc, kk, qq) asm("v_fma_mix_f32 %0, %1, %2, %0 op_sel:[0,0,0] op_sel_hi:[1,1,0]" : "+v"(acc) : "v"(kk), "v"(qq))
#define MIX_HH(acc, kk, qq) asm("v_fma_mix_f32 %0, %1, %2, %0 op_sel:[1,1,0] op_sel_hi:[1,1,0]" : "+v"(acc) : "v"(kk), "v"(qq))
#define MIX_LF(acc, vv, ee) asm("v_fma_mix_f32 %0, %1, %2, %0 op_sel:[0,0,0] op_sel_hi:[1,0,0]" : "+v"(acc) : "v"(vv), "v"(ee))
#define MIX_HF(acc, vv, ee) asm("v_fma_mix_f32 %0, %1, %2, %0 op_sel:[1,0,0] op_sel_hi:[1,0,0]" : "+v"(acc) : "v"(vv), "v"(ee))

// ---------------------------------------------------------------------------
// x transpose+convert: [B][192][NPIX] fp32 -> records [B][NPIX][192] f16.
// The y==0,z==0 block slice also converts both weight matrices to f16, and
// block (0,0,0) zeroes the OOB guard page.
// ---------------------------------------------------------------------------
__global__ __launch_bounds__(256) void convert_x(
    const float* __restrict__ x, _Float16* __restrict__ Xf,
    const float* __restrict__ w1, _Float16* __restrict__ Wf1,
    const float* __restrict__ w2, _Float16* __restrict__ Wf2,
    uint4* __restrict__ guard)
{
    __shared__ float t[32][65];
    const int b  = blockIdx.z;
    const int c0 = blockIdx.y * 32;
    const int p0 = blockIdx.x * 64;
    const int tid = threadIdx.x;

    if (blockIdx.y == 0 && blockIdx.z == 0) {
        const int f = blockIdx.x * 256 + tid;    // 0..36863
        #pragma unroll
        for (int u = 0; u < 4; ++u) {
            const int i = f * 4 + u;             // 0..147455
            if (i < 576 * 192) Wf1[i] = (_Float16)w1[i];
            else               Wf2[i - 576 * 192] = (_Float16)w2[i - 576 * 192];
        }
        if (blockIdx.x == 0 && tid < 64)
            guard[tid] = make_uint4(0u, 0u, 0u, 0u);
    }

    const int pl = tid & 63;
    #pragma unroll
    for (int i = 0; i < 8; ++i) {
        const int c = i * 4 + (tid >> 6);
        t[c][pl] = x[((size_t)b * 192 + c0 + c) * NPIX + p0 + pl];
    }
    __syncthreads();
    const int p  = tid >> 2;
    const int cq = (tid & 3) * 8;
    f16x8 vh;
    #pragma unroll
    for (int j = 0; j < 8; ++j)
        vh[j] = (_Float16)t[cq + j][p];
    *(f16x8*)(Xf + ((size_t)b * NPIX + p0 + p) * 192 + c0 + cq) = vh;
}

// ---------------------------------------------------------------------------
// f16 MFMA GEMM (1-product): Y[b][m][n] = sum_k W[m][k] * X[b][n][k]
// m97 structure: BM=64 BN=128 BK=64; global_load_lds staging + chunk-XOR swizzle.
// 1D grid, XCD-owned n-ranges: XCD x owns n-tiles [9x, 9x+9).
// MODE 0: Y float planes [B][M][NPIX].  MODE 1: f16 octet-planes [B][M/8][NPIX] x uint4.
// ---------------------------------------------------------------------------
template<int MODE, int M>
__global__ __launch_bounds__(256) void gemm_mfma(
    const _Float16* __restrict__ A, const _Float16* __restrict__ B,
    void* __restrict__ Yv)
{
    constexpr int MT = M / 64;                  // m-tiles
    __shared__ _Float16 sA[64 * 64];            // 8 KB
    __shared__ _Float16 sB[128 * 64];           // 16 KB

    const int orig = blockIdx.x;
    const int xcd = orig & 7;
    const int l = orig >> 3;                    // 0 .. MT*4*9-1
    const int m0 = (l % MT) * 64;
    const int b  = (l / MT) & 3;
    const int n0 = (xcd * 9 + l / (MT * 4)) * 128;

    const int tid  = threadIdx.x;
    const int lane = tid & 63;
    const int wid  = tid >> 6;
    const int wr = wid >> 1, wc = wid & 1;
    const int lr = lane & 15;
    const int kg = lane >> 4;

    const char* gA = (const char*)A + (size_t)m0 * 384;
    const char* gB = (const char*)B + ((size_t)b * NPIX + n0) * 384;

    f32x4 acc[2][4];
    #pragma unroll
    for (int mf = 0; mf < 2; ++mf)
        #pragma unroll
        for (int nf = 0; nf < 4; ++nf)
            acc[mf][nf] = (f32x4){0.f, 0.f, 0.f, 0.f};

    for (int ks = 0; ks < 3; ++ks) {
        if (ks) __syncthreads();
        const int kb = ks * 128;
        #pragma unroll
        for (int it = 0; it < 2; ++it) {
            const int d  = it * 256 + tid;
            const int rd = d >> 3, cd = d & 7;
            const size_t src = (size_t)rd * 384 + kb + ((cd ^ (rd & 7)) << 4);
            cp16((char*)sA + d * 16, gA + src);
        }
        #pragma unroll
        for (int it = 0; it < 4; ++it) {
            const int d  = it * 256 + tid;
            const int rd = d >> 3, cd = d & 7;
            const size_t src = (size_t)rd * 384 + kb + ((cd ^ (rd & 7)) << 4);
            cp16((char*)sB + d * 16, gB + src);
        }
        __syncthreads();
        #pragma unroll
        for (int s = 0; s < 2; ++s) {
            f16x8 aH[2], bH[4];
            #pragma unroll
            for (int mf = 0; mf < 2; ++mf) {
                const int row = wr * 32 + mf * 16 + lr;
                const int c = (s * 4 + kg) ^ (row & 7);
                aH[mf] = *(const f16x8*)((const char*)sA + row * 128 + c * 16);
            }
            #pragma unroll
            for (int nf = 0; nf < 4; ++nf) {
                const int row = wc * 64 + nf * 16 + lr;
                const int c = (s * 4 + kg) ^ (row & 7);
                bH[nf] = *(const f16x8*)((const char*)sB + row * 128 + c * 16);
            }
            #pragma unroll
            for (int mf = 0; mf < 2; ++mf)
                #pragma unroll
                for (int nf = 0; nf < 4; ++nf)
                    acc[mf][nf] = __builtin_amdgcn_mfma_f32_16x16x32_f16(aH[mf], bH[nf], acc[mf][nf], 0, 0, 0);
        }
    }

    // D layout: col = lane&15, row = (lane>>4)*4 + r
    if (MODE == 0) {
        float* Yb = (float*)Yv + ((size_t)b * M + m0 + wr * 32) * NPIX + n0 + wc * 64;
        #pragma unroll
        for (int mf = 0; mf < 2; ++mf)
            #pragma unroll
            for (int r = 0; r < 4; ++r) {
                const int row = mf * 16 + kg * 4 + r;
                #pragma unroll
                for (int nf = 0; nf < 4; ++nf)
                    Yb[(size_t)row * NPIX + nf * 16 + lr] = acc[mf][nf][r];
            }
    } else {
        #pragma unroll
        for (int mf = 0; mf < 2; ++mf) {
            const int cbase = m0 + wr * 32 + mf * 16 + kg * 4;
            unsigned* Yq = (unsigned*)Yv
                + (((size_t)b * 72 + (cbase >> 3)) * NPIX + n0 + wc * 64 + lr) * 4
                + ((kg & 1) << 1);
            #pragma unroll
            for (int nf = 0; nf < 4; ++nf) {
                Yq[(nf * 16) * 4 + 0] = packf16(acc[mf][nf][0], acc[mf][nf][1]);
                Yq[(nf * 16) * 4 + 1] = packf16(acc[mf][nf][2], acc[mf][nf][3]);
            }
        }
    }
}

// ---------------------------------------------------------------------------
// LDS-tiled neighborhood attention, f16 octet planes. 16x16 tiles, 256 thr,
// 864 blocks XCD-chunked. (Session measured-best configuration.)
// DB=true: double-buffered staging (L*256-strided padded regions), counted
// vmcnt + raw s_barrier. DB=false (heads (7,3),(9,2)): syncthreads single-buf.
// BORDER=false (tiles with full halo in-bounds): unguarded staging.
// s_setprio(1) around the fma_mix bursts.
// 8 rounds: r=0..3 QK octets, r=4..7 PV octets. Output f16 records.
// ---------------------------------------------------------------------------
#define TW 16
#define TH 16

template<int KSZ, int DIL, bool DB, int L, bool BORDER>
__device__ __forceinline__ void attn_body(
    const uint4* __restrict__ Qq, const uint4* __restrict__ Kq,
    const uint4* __restrict__ Vq, const float* __restrict__ bias,
    const uint4* __restrict__ guard,
    _Float16* __restrict__ oh, int h0, int w0,
    uint4* __restrict__ bufs,
    unsigned (* __restrict__ out_lds)[256])
{
    constexpr int CC  = KSZ / 2;
    constexpr int HAL = CC * DIL;
    constexpr int R   = TH + 2 * HAL;
    constexpr int C   = TW + 2 * HAL;
    constexpr int RC  = R * C;
    constexpr int NN  = KSZ * KSZ;

    const int tid = threadIdx.x;
    const int tx = tid & 15;
    const int ty = tid >> 4;               // 0..15
    const int pix = (h0 + ty) * WDIM + (w0 + tx);
    const int lb = ty * C + tx;

    uint4 qv[4];
    #pragma unroll
    for (int p = 0; p < 4; ++p) qv[p] = Qq[(size_t)p * NPIX + pix];

    // bias folded into score init: e = exp2((dot + bias/scale) * scale*log2e)
    float score[NN];
    #pragma unroll
    for (int n = 0; n < NN; ++n) score[n] = bias[n] * 5.656854249492381f;

    auto STAGE = [&](int r) {
        const uint4* src = (r < 4) ? (Kq + (size_t)r * NPIX)
                                   : (Vq + (size_t)(r - 4) * NPIX);
        uint4* dst = bufs + (DB ? ((r & 1) * (L * 256)) : 0);
        #pragma unroll
        for (int it = 0; it < L; ++it) {
            const int idx = it * 256 + tid;
            const int rr = idx / C, cc = idx - rr * C;
            const int gh = h0 - HAL + rr, gw = w0 - HAL + cc;
            if constexpr (BORDER) {
                const bool ok = (idx < RC) && ((unsigned)gh < (unsigned)HDIM)
                                           && ((unsigned)gw < (unsigned)WDIM);
                const uint4* s = ok ? (src + gh * WDIM + gw) : guard;
                cp16(dst + idx, s);
            } else {
                if (idx < RC) cp16(dst + idx, src + gh * WDIM + gw);
            }
        }
    };

    auto QK = [&](const uint4* buf, int oct) {
        const uint4 q = qv[oct];
        __builtin_amdgcn_s_setprio(1);
        #pragma unroll
        for (int i = 0; i < KSZ; ++i)
            #pragma unroll
            for (int j = 0; j < KSZ; ++j) {
                const uint4 k8 = buf[lb + i * DIL * C + j * DIL];
                float s = score[i * KSZ + j];
                MIX_LL(s, k8.x, q.x); MIX_HH(s, k8.x, q.x);
                MIX_LL(s, k8.y, q.y); MIX_HH(s, k8.y, q.y);
                MIX_LL(s, k8.z, q.z); MIX_HH(s, k8.z, q.z);
                MIX_LL(s, k8.w, q.w); MIX_HH(s, k8.w, q.w);
                score[i * KSZ + j] = s;
            }
        __builtin_amdgcn_s_setprio(0);
    };

    float inv = 0.f;
    auto SOFTMAX = [&]() {
        float l = 0.f;
        #pragma unroll
        for (int n = 0; n < NN; ++n) {
            // scale * log2(e)
            const float e = exp2f(score[n] * 0.25506113952980654f);
            l += e;
            score[n] = e;
        }
        inv = 1.f / l;
    };

    auto PV = [&](const uint4* buf, int oct) {
        float a0 = 0.f, a1 = 0.f, a2 = 0.f, a3 = 0.f;
        float a4 = 0.f, a5 = 0.f, a6 = 0.f, a7 = 0.f;
        __builtin_amdgcn_s_setprio(1);
        #pragma unroll
        for (int i = 0; i < KSZ; ++i)
            #pragma unroll
            for (int j = 0; j < KSZ; ++j) {
                const uint4 v8 = buf[lb + i * DIL * C + j * DIL];
                const float e = score[i * KSZ + j];
                MIX_LF(a0, v8.x, e); MIX_HF(a1, v8.x, e);
                MIX_LF(a2, v8.y, e); MIX_HF(a3, v8.y, e);
                MIX_LF(a4, v8.z, e); MIX_HF(a5, v8.z, e);
                MIX_LF(a6, v8.w, e); MIX_HF(a7, v8.w, e);
            }
        __builtin_amdgcn_s_setprio(0);
        const int rr = oct & 1;
        out_lds[rr * 4 + 0][tid] = packf16(a0 * inv, a1 * inv);
        out_lds[rr * 4 + 1][tid] = packf16(a2 * inv, a3 * inv);
        out_lds[rr * 4 + 2][tid] = packf16(a4 * inv, a5 * inv);
        out_lds[rr * 4 + 3][tid] = packf16(a6 * inv, a7 * inv);
    };

    auto COOP = [&](int half) {     // coalesced half-record write (16 ch)
        #pragma unroll
        for (int it = 0; it < 2; ++it) {
            const int linear = it * 256 + tid;
            const int px = linear >> 1;        // 0..255
            const int c  = linear & 1;
            const int gpix = (h0 + (px >> 4)) * WDIM + w0 + (px & 15);
            uint4 val = make_uint4(out_lds[c * 4 + 0][px], out_lds[c * 4 + 1][px],
                                   out_lds[c * 4 + 2][px], out_lds[c * 4 + 3][px]);
            *((uint4*)((unsigned*)(oh + (size_t)gpix * 192)) + half * 2 + c) = val;
        }
    };

    if constexpr (DB) {
        STAGE(0);
        #pragma unroll
        for (int r = 0; r < 8; ++r) {
            if (r < 7) STAGE(r + 1);
            if (r < 7) waitcnt_vm<L>(); else waitcnt_vm<0>();
            __builtin_amdgcn_s_barrier();
            __builtin_amdgcn_sched_barrier(0);
            const uint4* buf = bufs + (r & 1) * (L * 256);
            if (r < 4) {
                QK(buf, r);
                if (r == 3) SOFTMAX();
            } else {
                PV(buf, r - 4);
                asm volatile("s_waitcnt lgkmcnt(0)" ::: "memory");
                __builtin_amdgcn_sched_barrier(0);
            }
            __builtin_amdgcn_s_barrier();
            __builtin_amdgcn_sched_barrier(0);
            if (r == 5) COOP(0);
            if (r == 7) COOP(1);
        }
    } else {
        #pragma unroll
        for (int r = 0; r < 8; ++r) {
            __syncthreads();
            if (r == 6) COOP(0);
            STAGE(r);
            __syncthreads();
            const uint4* buf = bufs;
            if (r < 4) {
                QK(buf, r);
                if (r == 3) SOFTMAX();
            } else {
                PV(buf, r - 4);
            }
        }
        __syncthreads();
        COOP(1);
    }
}

// 864 blocks, XCD-chunked: XCD x owns wgs [x*108,(x+1)*108) = 3 panels
// (big/mid/small k) x 36 tiles of 16x16. Interior tiles (txt,tyt in [1,4]:
// halo slack 16 >= HAL for all heads) take the unguarded staging path.
__global__ __launch_bounds__(256) void attn_kernel(
    const uint4* __restrict__ qkv, Bias6 bs, _Float16* __restrict__ ATf,
    const uint4* __restrict__ guard)
{
    __shared__ uint4 bufs[1536];             // 24 KB
    __shared__ unsigned out_lds[8][256];     // 8 KB  -> 32 KB total

    const int orig = blockIdx.x;
    const int wg = (orig & 7) * 108 + (orig >> 3);
    const int panel = wg / 36;
    const int tile = wg - panel * 36;
    const int chunk = panel / 3, slot = panel - chunk * 3;
    int head, b;
    if (slot == 0)      { head = 4 + (chunk >> 2); b = chunk & 3; }
    else if (slot == 1) { head = 2 + (chunk >> 2); b = chunk & 3; }
    else                { head = (chunk < 4) ? 1 : 0; b = chunk & 3; }
    const int txt = tile % 6, tyt = tile / 6;   // 6 x 6 tiles of 16x16
    const int w0 = txt * TW, h0 = tyt * TH;
    const bool border = (txt == 0) | (txt == 5) | (tyt == 0) | (tyt == 5);

    const uint4* base = qkv + (size_t)b * 72 * NPIX;
    const uint4* Qq = base + (size_t)(head * 4) * NPIX;
    const uint4* Kq = base + (size_t)(24 + head * 4) * NPIX;
    const uint4* Vq = base + (size_t)(48 + head * 4) * NPIX;
    _Float16* oh = ATf + (size_t)b * NPIX * 192 + head * 32;
    const float* bias = bs.p[head];

    if (border) {
        switch (head) {
            case 0: attn_body<3, 1, true, 2, true>(Qq, Kq, Vq, bias, guard, oh, h0, w0, bufs, out_lds); break;
            case 1: attn_body<5, 2, true, 3, true>(Qq, Kq, Vq, bias, guard, oh, h0, w0, bufs, out_lds); break;
            case 2: attn_body<7, 1, true, 2, true>(Qq, Kq, Vq, bias, guard, oh, h0, w0, bufs, out_lds); break;
            case 3: attn_body<7, 3, false, 5, true>(Qq, Kq, Vq, bias, guard, oh, h0, w0, bufs, out_lds); break;
            case 4: attn_body<9, 1, true, 3, true>(Qq, Kq, Vq, bias, guard, oh, h0, w0, bufs, out_lds); break;
            case 5: attn_body<9, 2, false, 4, true>(Qq, Kq, Vq, bias, guard, oh, h0, w0, bufs, out_lds); break;
        }
    } else {
        switch (head) {
            case 0: attn_body<3, 1, true, 2, false>(Qq, Kq, Vq, bias, guard, oh, h0, w0, bufs, out_lds); break;
            case 1: attn_body<5, 2, true, 3, false>(Qq, Kq, Vq, bias, guard, oh, h0, w0, bufs, out_lds); break;
            case 2: attn_body<7, 1, true, 2, false>(Qq, Kq, Vq, bias, guard, oh, h0, w0, bufs, out_lds); break;
            case 3: attn_body<7, 3, false, 5, false>(Qq, Kq, Vq, bias, guard, oh, h0, w0, bufs, out_lds); break;
            case 4: attn_body<9, 1, true, 3, false>(Qq, Kq, Vq, bias, guard, oh, h0, w0, bufs, out_lds); break;
            case 5: attn_body<9, 2, false, 4, false>(Qq, Kq, Vq, bias, guard, oh, h0, w0, bufs, out_lds); break;
        }
    }
}

// ---------------------------------------------------------------------------
extern "C" void kernel_launch(void* const* d_in, const int* in_sizes, int n_in,
                              void* d_out, int out_size, void* d_ws, size_t ws_size,
                              hipStream_t stream) {
    const float* x     = (const float*)d_in[0];   // [4][192][96][96]
    const float* w_qkv = (const float*)d_in[1];   // [576][192]
    const float* w_out = (const float*)d_in[2];   // [192][192]
    Bias6 bs;
    for (int i = 0; i < 6; ++i) bs.p[i] = (const float*)d_in[3 + i];
    float* out = (float*)d_out;                   // [4][192][96][96]

    char* ws = (char*)d_ws;
    uint4*    QKV = (uint4*)ws;         ws += (size_t)BATCH * 72 * NPIX * 16;   // 42.5 MB
    _Float16* Xf  = (_Float16*)ws;      ws += (size_t)BATCH * NPIX * 192 * 2;   // 14.2 MB
    _Float16* ATf = (_Float16*)ws;      ws += (size_t)BATCH * NPIX * 192 * 2;   // 14.2 MB
    _Float16* Wf1 = (_Float16*)ws;      ws += (size_t)576 * 192 * 2;
    _Float16* Wf2 = (_Float16*)ws;      ws += (size_t)192 * 192 * 2;
    uint4* guard  = (uint4*)ws;         ws += 1024;                              // zero page

    // 1) x transpose+convert to f16 records (+ weight convert + guard zero)
    convert_x<<<dim3(NPIX / 64, 192 / 32, BATCH), 256, 0, stream>>>(
        x, Xf, w_qkv, Wf1, w_out, Wf2, guard);

    // 2) qkv projection (f16 MFMA) -> f16 octet-planes [B][72][NPIX] x uint4
    gemm_mfma<1, 576><<<dim3(8 * (576 / 64) * 4 * 9), 256, 0, stream>>>(
        Wf1, Xf, (void*)QKV);

    // 3) neighborhood attention -> f16 records (coalesced)
    attn_kernel<<<dim3(864), 256, 0, stream>>>(QKV, bs, ATf, guard);

    // 4) out projection (f16 MFMA) -> d_out fp32 planes
    gemm_mfma<0, 192><<<dim3(8 * (192 / 64) * 4 * 9), 256, 0, stream>>>(
        Wf2, ATf, (void*)out);
}